// Round 1
// baseline (2513.356 us; speedup 1.0000x reference)
//
#include <hip/hip_runtime.h>
#include <cstdint>
#include <cstddef>

#define NG 512        // NUM_GRAPHS
#define NN 131072     // N_NODES
#define NE 4194304    // N_EDGES
#define FIN 54        // F_IN
#define HG 16         // H_GCN
#define HL 32         // H_LSTM
#define NC 192        // N_CLASSES
#define TS 1024       // MAX_SEQ_LEN

__device__ __forceinline__ float sigf(float x){ return 1.0f/(1.0f + __expf(-x)); }
__device__ __forceinline__ float tanhfast(float x){ return 1.0f - 2.0f/(__expf(2.0f*x) + 1.0f); }

// ---------------- init: deg=1 (self loop), counts=0 ----------------
__global__ void k_init(float* __restrict__ deg, int* __restrict__ counts){
  int i = blockIdx.x*256 + threadIdx.x;
  if (i < NN) deg[i] = 1.0f;
  if (i < NG) counts[i] = 0;
}

// ---------------- degree (edges) + per-graph node counts ----------------
__global__ void k_degcnt(const int* __restrict__ ei, const int* __restrict__ batch,
                         float* __restrict__ deg, int* __restrict__ counts){
  int i = blockIdx.x*256 + threadIdx.x;
  if (i < NE) atomicAdd(&deg[ei[NE + i]], 1.0f);
  if (i < NN) atomicAdd(&counts[batch[i]], 1);
}

// ---------------- exclusive scan of counts -> starts (1 block, 512 thr) ----------------
__global__ void k_scan(const int* __restrict__ counts, int* __restrict__ starts){
  __shared__ int sc[NG];
  int t = threadIdx.x;
  sc[t] = counts[t]; __syncthreads();
  for (int off = 1; off < NG; off <<= 1){
    int v = (t >= off) ? sc[t-off] : 0;
    __syncthreads();
    sc[t] += v;
    __syncthreads();
  }
  starts[t] = sc[t] - counts[t];
}

__global__ void k_dinv(const float* __restrict__ deg, float* __restrict__ dinv){
  int i = blockIdx.x*256 + threadIdx.x;
  if (i < NN) dinv[i] = 1.0f / sqrtf(fmaxf(deg[i], 1.0f));
}

// ---------------- xa = x @ w1  (no bias yet) ----------------
__global__ void k_lin1(const float* __restrict__ x, const float* __restrict__ w1,
                       float* __restrict__ xa){
  __shared__ float w[FIN*HG];
  int tid = threadIdx.x;
  for (int i = tid; i < FIN*HG; i += 256) w[i] = w1[i];
  __syncthreads();
  int id = blockIdx.x*256 + tid;
  if (id >= NN*HG) return;
  int node = id >> 4, f = id & 15;
  const float* xr = x + (size_t)node*FIN;
  float acc = 0.0f;
#pragma unroll
  for (int k = 0; k < FIN; k++) acc = fmaf(xr[k], w[k*HG + f], acc);
  xa[id] = acc;
}

// ---------------- agg = v * dinv^2 (self-loop term) ----------------
__global__ void k_selfinit(const float* __restrict__ v, const float* __restrict__ dinv,
                           float* __restrict__ agg){
  int id = blockIdx.x*256 + threadIdx.x;
  if (id >= NN*HG) return;
  float di = dinv[id >> 4];
  agg[id] = v[id] * di * di;
}

// ---------------- agg[dst] += v[src]*dinv[src]*dinv[dst] over edges ----------------
__global__ void k_scatter(const int* __restrict__ ei, const float* __restrict__ v,
                          const float* __restrict__ dinv, float* __restrict__ agg){
  int id = blockIdx.x*256 + threadIdx.x;
  if (id >= NE*HG) return;
  int e = id >> 4, f = id & 15;
  int s = ei[e], d = ei[NE + e];
  float nv = dinv[s] * dinv[d];
  atomicAdd(&agg[d*HG + f], v[s*HG + f] * nv);
}

// ---------------- hb = relu(agg + b1) @ w2 ----------------
__global__ void k_relu_lin(const float* __restrict__ agg, const float* __restrict__ b1,
                           const float* __restrict__ w2, float* __restrict__ hb){
  __shared__ float w[HG*HG];
  __shared__ float bb[HG];
  int tid = threadIdx.x;
  if (tid < HG*HG) w[tid] = w2[tid];
  if (tid < HG) bb[tid] = b1[tid];
  __syncthreads();
  int id = blockIdx.x*256 + tid;
  if (id >= NN*HG) return;
  int node = id >> 4, f = id & 15;
  const float* ar = agg + (size_t)node*HG;
  float acc = 0.0f;
#pragma unroll
  for (int k = 0; k < HG; k++){
    float h = fmaxf(ar[k] + bb[k], 0.0f);
    acc = fmaf(h, w[k*HG + f], acc);
  }
  hb[id] = acc;
}

// ---------------- h2 = relu(agg + b2) ----------------
__global__ void k_relu(const float* __restrict__ agg, const float* __restrict__ b2,
                       float* __restrict__ h2){
  int id = blockIdx.x*256 + threadIdx.x;
  if (id >= NN*HG) return;
  h2[id] = fmaxf(agg[id] + b2[id & 15], 0.0f);
}

// ---------------- BiLSTM layer 0: one wave per (graph, dir) ----------------
// Lane layout: j = lane&31, half = lane>>5. Gates: gA = half*32+j (i or f),
// gB = 64+half*32+j (g or o). half==1 lanes own c_j, h_j.
__global__ __launch_bounds__(64, 1) void k_lstm0(
    const float* __restrict__ h2, const int* __restrict__ starts, const int* __restrict__ counts,
    const float* __restrict__ wih, const float* __restrict__ whh,
    const float* __restrict__ bih, const float* __restrict__ bhh,
    float* __restrict__ out0)
{
  const int g = blockIdx.x >> 1, dir = blockIdx.x & 1;
  const int lane = threadIdx.x;
  const int j = lane & 31, half = lane >> 5;
  const int gA = half*32 + j, gB = 64 + half*32 + j;
  const float* wihd = wih + (size_t)dir*128*HG;
  const float* whhd = whh + (size_t)dir*128*HL;
  float wAi[HG], wBi[HG], wAh[HL], wBh[HL];
#pragma unroll
  for (int k = 0; k < HG; k++){ wAi[k] = wihd[gA*HG + k]; wBi[k] = wihd[gB*HG + k]; }
#pragma unroll
  for (int k = 0; k < HL; k++){ wAh[k] = whhd[gA*HL + k]; wBh[k] = whhd[gB*HL + k]; }
  const float pbA = bih[dir*128 + gA] + bhh[dir*128 + gA];
  const float pbB = bih[dir*128 + gB] + bhh[dir*128 + gB];
  int cnt = counts[g]; if (cnt > TS) cnt = TS;
  const int s0 = starts[g];
  __shared__ float hl[HL];
  if (lane < HL) hl[lane] = 0.0f;
  __syncthreads();
  float c = 0.0f;
  float* outg = out0 + (size_t)g*TS*64 + dir*32;

  // backward dir: with all-zero effective biases, zero input keeps state exactly 0,
  // so steps t >= cnt produce h == 0. Guard with a runtime bias check.
  unsigned long long zb = __ballot(pbA == 0.0f && pbB == 0.0f);
  bool allzero = (zb == 0xFFFFFFFFFFFFFFFFull);

  int t0, t1, dt;
  if (dir == 0){ t0 = 0; t1 = TS; dt = 1; }
  else if (allzero){
    for (int t = cnt; t < TS; ++t) if (half) outg[(size_t)t*64 + j] = 0.0f;
    t0 = cnt - 1; t1 = -1; dt = -1;
  } else { t0 = TS - 1; t1 = -1; dt = -1; }

  for (int t = t0; t != t1; t += dt){
    float a0 = pbA, a1 = 0.0f, b0 = pbB, b1 = 0.0f;
    if (t < cnt){
      const float4* xr = (const float4*)(h2 + (size_t)(s0 + t)*HG);
      float4 q0 = xr[0], q1 = xr[1], q2 = xr[2], q3 = xr[3];
      float xv[16] = {q0.x,q0.y,q0.z,q0.w, q1.x,q1.y,q1.z,q1.w,
                      q2.x,q2.y,q2.z,q2.w, q3.x,q3.y,q3.z,q3.w};
#pragma unroll
      for (int k = 0; k < 16; k += 2){
        a0 = fmaf(xv[k],   wAi[k],   a0); a1 = fmaf(xv[k+1], wAi[k+1], a1);
        b0 = fmaf(xv[k],   wBi[k],   b0); b1 = fmaf(xv[k+1], wBi[k+1], b1);
      }
    }
    const float4* h4 = (const float4*)hl;
#pragma unroll
    for (int k4 = 0; k4 < 8; k4++){
      float4 hv = h4[k4];
      a0 = fmaf(hv.x, wAh[4*k4+0], a0); a1 = fmaf(hv.y, wAh[4*k4+1], a1);
      a0 = fmaf(hv.z, wAh[4*k4+2], a0); a1 = fmaf(hv.w, wAh[4*k4+3], a1);
      b0 = fmaf(hv.x, wBh[4*k4+0], b0); b1 = fmaf(hv.y, wBh[4*k4+1], b1);
      b0 = fmaf(hv.z, wBh[4*k4+2], b0); b1 = fmaf(hv.w, wBh[4*k4+3], b1);
    }
    float aA = a0 + a1, aB = b0 + b1;
    float sA = sigf(aA);                       // half0: sig(i); half1: sig(f)
    float u  = half ? aB : (aB + aB);
    float sB = 1.0f/(1.0f + __expf(-u));
    float vB = half ? sB : (sB + sB - 1.0f);   // half0: tanh(g); half1: sig(o)
    float p  = sA * vB;                        // half0: sig(i)*tanh(g)
    float pj = __shfl(p, j);                   // lane 32+j pulls p_j from lane j
    c = fmaf(sA, c, pj);                       // meaningful on half1
    float h = vB * tanhfast(c);                // half1: sig(o)*tanh(c)
    __syncthreads();
    if (half){ hl[j] = h; outg[(size_t)t*64 + j] = h; }
    __syncthreads();
  }
}

// ---------------- BiLSTM layer 1 + mean pooling (no sequence output) ----------------
__global__ __launch_bounds__(64, 1) void k_lstm1(
    const float* __restrict__ gl0, const float* __restrict__ wih, const float* __restrict__ whh,
    const float* __restrict__ bih, const float* __restrict__ bhh,
    float* __restrict__ pooled)
{
  const int g = blockIdx.x >> 1, dir = blockIdx.x & 1;
  const int lane = threadIdx.x;
  const int j = lane & 31, half = lane >> 5;
  const int gA = half*32 + j, gB = 64 + half*32 + j;
  const float* wihd = wih + (size_t)dir*128*64;
  const float* whhd = whh + (size_t)dir*128*HL;
  float wAi[64], wBi[64], wAh[HL], wBh[HL];
#pragma unroll
  for (int k = 0; k < 64; k++){ wAi[k] = wihd[gA*64 + k]; wBi[k] = wihd[gB*64 + k]; }
#pragma unroll
  for (int k = 0; k < HL; k++){ wAh[k] = whhd[gA*HL + k]; wBh[k] = whhd[gB*HL + k]; }
  const float pbA = bih[dir*128 + gA] + bhh[dir*128 + gA];
  const float pbB = bih[dir*128 + gB] + bhh[dir*128 + gB];
  __shared__ float hl[HL];
  __shared__ float xs[64];
  if (lane < HL) hl[lane] = 0.0f;
  __syncthreads();
  float c = 0.0f, hsum = 0.0f;
  const float* gin = gl0 + (size_t)g*TS*64;

  for (int tt = 0; tt < TS; ++tt){
    int t = dir ? (TS - 1 - tt) : tt;
    xs[lane] = gin[(size_t)t*64 + lane];
    __syncthreads();
    float a0 = pbA, a1 = 0.0f, a2 = 0.0f, a3 = 0.0f;
    float b0 = pbB, b1 = 0.0f, b2 = 0.0f, b3 = 0.0f;
    const float4* x4 = (const float4*)xs;
#pragma unroll
    for (int k4 = 0; k4 < 16; k4++){
      float4 xv = x4[k4];
      a0 = fmaf(xv.x, wAi[4*k4+0], a0); a1 = fmaf(xv.y, wAi[4*k4+1], a1);
      a2 = fmaf(xv.z, wAi[4*k4+2], a2); a3 = fmaf(xv.w, wAi[4*k4+3], a3);
      b0 = fmaf(xv.x, wBi[4*k4+0], b0); b1 = fmaf(xv.y, wBi[4*k4+1], b1);
      b2 = fmaf(xv.z, wBi[4*k4+2], b2); b3 = fmaf(xv.w, wBi[4*k4+3], b3);
    }
    const float4* h4 = (const float4*)hl;
#pragma unroll
    for (int k4 = 0; k4 < 8; k4++){
      float4 hv = h4[k4];
      a0 = fmaf(hv.x, wAh[4*k4+0], a0); a1 = fmaf(hv.y, wAh[4*k4+1], a1);
      a2 = fmaf(hv.z, wAh[4*k4+2], a2); a3 = fmaf(hv.w, wAh[4*k4+3], a3);
      b0 = fmaf(hv.x, wBh[4*k4+0], b0); b1 = fmaf(hv.y, wBh[4*k4+1], b1);
      b2 = fmaf(hv.z, wBh[4*k4+2], b2); b3 = fmaf(hv.w, wBh[4*k4+3], b3);
    }
    float aA = (a0 + a1) + (a2 + a3), aB = (b0 + b1) + (b2 + b3);
    float sA = sigf(aA);
    float u  = half ? aB : (aB + aB);
    float sB = 1.0f/(1.0f + __expf(-u));
    float vB = half ? sB : (sB + sB - 1.0f);
    float p  = sA * vB;
    float pj = __shfl(p, j);
    c = fmaf(sA, c, pj);
    float h = vB * tanhfast(c);
    __syncthreads();
    if (half){ hl[j] = h; hsum += h; }
    __syncthreads();
  }
  if (half) pooled[(size_t)g*64 + dir*32 + j] = hsum * (1.0f/(float)TS);
}

// ---------------- FC: out = pooled @ fc_w + fc_b ----------------
__global__ void k_fc(const float* __restrict__ pooled, const float* __restrict__ fcw,
                     const float* __restrict__ fcb, float* __restrict__ out){
  __shared__ float p[64];
  int g = blockIdx.x, cix = threadIdx.x;
  if (cix < 64) p[cix] = pooled[(size_t)g*64 + cix];
  __syncthreads();
  float acc = fcb[cix];
#pragma unroll
  for (int k = 0; k < 64; k++) acc = fmaf(p[k], fcw[k*NC + cix], acc);
  out[(size_t)g*NC + cix] = acc;
}

extern "C" void kernel_launch(void* const* d_in, const int* in_sizes, int n_in,
                              void* d_out, int out_size, void* d_ws, size_t ws_size,
                              hipStream_t stream) {
  const float* x        = (const float*)d_in[0];
  const int*   ei       = (const int*)  d_in[1];
  const int*   batch    = (const int*)  d_in[2];
  const float* gcn_w1   = (const float*)d_in[3];
  const float* gcn_b1   = (const float*)d_in[4];
  const float* gcn_w2   = (const float*)d_in[5];
  const float* gcn_b2   = (const float*)d_in[6];
  const float* l0_wih   = (const float*)d_in[7];
  const float* l0_whh   = (const float*)d_in[8];
  const float* l0_bih   = (const float*)d_in[9];
  const float* l0_bhh   = (const float*)d_in[10];
  const float* l1_wih   = (const float*)d_in[11];
  const float* l1_whh   = (const float*)d_in[12];
  const float* l1_bih   = (const float*)d_in[13];
  const float* l1_bhh   = (const float*)d_in[14];
  const float* fc_w     = (const float*)d_in[15];
  const float* fc_b     = (const float*)d_in[16];
  float* out = (float*)d_out;

  // workspace layout (floats)
  float* ws   = (float*)d_ws;
  float* B0   = ws;                    // N*16 : xa -> agg2
  float* B1   = B0 + (size_t)NN*HG;    // N*16 : agg1 -> h2
  float* B2   = B1 + (size_t)NN*HG;    // N*16 : hb
  float* deg  = B2 + (size_t)NN*HG;    // N
  float* dinv = deg + NN;              // N
  int*   counts = (int*)(dinv + NN);   // 512
  int*   starts = counts + NG;         // 512
  float* pooled = (float*)(starts + NG);      // 512*64
  float* out0   = pooled + (size_t)NG*64;     // 512*1024*64
  size_t needed = ((size_t)(out0 - ws) + (size_t)NG*TS*64) * sizeof(float);
  if (ws_size < needed) return;  // fail loudly (poisoned d_out) rather than corrupt

  k_init   <<<(NN+255)/256, 256, 0, stream>>>(deg, counts);
  k_degcnt <<<(NE+255)/256, 256, 0, stream>>>(ei, batch, deg, counts);
  k_scan   <<<1, NG, 0, stream>>>(counts, starts);
  k_dinv   <<<(NN+255)/256, 256, 0, stream>>>(deg, dinv);
  k_lin1   <<<(NN*HG)/256, 256, 0, stream>>>(x, gcn_w1, B0);
  k_selfinit<<<(NN*HG)/256, 256, 0, stream>>>(B0, dinv, B1);
  k_scatter<<<(NE*HG)/256, 256, 0, stream>>>(ei, B0, dinv, B1);
  k_relu_lin<<<(NN*HG)/256, 256, 0, stream>>>(B1, gcn_b1, gcn_w2, B2);
  k_selfinit<<<(NN*HG)/256, 256, 0, stream>>>(B2, dinv, B0);
  k_scatter<<<(NE*HG)/256, 256, 0, stream>>>(ei, B2, dinv, B0);
  k_relu   <<<(NN*HG)/256, 256, 0, stream>>>(B0, gcn_b2, B1);
  k_lstm0  <<<NG*2, 64, 0, stream>>>(B1, starts, counts, l0_wih, l0_whh, l0_bih, l0_bhh, out0);
  k_lstm1  <<<NG*2, 64, 0, stream>>>(out0, l1_wih, l1_whh, l1_bih, l1_bhh, pooled);
  k_fc     <<<NG, NC, 0, stream>>>(pooled, fc_w, fc_b, out);
}

// Round 2
// 2234.290 us; speedup vs baseline: 1.1249x; 1.1249x over previous
//
#include <hip/hip_runtime.h>
#include <cstdint>
#include <cstddef>

#define NG 512        // NUM_GRAPHS
#define NN 131072     // N_NODES
#define NE 4194304    // N_EDGES
#define FIN 54        // F_IN
#define HG 16         // H_GCN
#define HL 32         // H_LSTM
#define NC 192        // N_CLASSES
#define TS 1024       // MAX_SEQ_LEN

__device__ __forceinline__ float rcpf(float x){ return __builtin_amdgcn_rcpf(x); }
__device__ __forceinline__ float sigf(float x){ return rcpf(1.0f + __expf(-x)); }
__device__ __forceinline__ float tanhfast(float x){ return 1.0f - 2.0f*rcpf(__expf(2.0f*x) + 1.0f); }
// broadcast lane l's value of v to all lanes (SGPR result)
__device__ __forceinline__ float rl(float v, int l){
  return __uint_as_float((unsigned)__builtin_amdgcn_readlane((int)__float_as_uint(v), l));
}

// repetition macros
#define RL1_16(M) M(0) M(1) M(2) M(3) M(4) M(5) M(6) M(7) M(8) M(9) M(10) M(11) M(12) M(13) M(14) M(15)
#define RL1_32(M) RL1_16(M) M(16) M(17) M(18) M(19) M(20) M(21) M(22) M(23) M(24) M(25) M(26) M(27) M(28) M(29) M(30) M(31)
#define RL1_64(M) RL1_32(M) M(32) M(33) M(34) M(35) M(36) M(37) M(38) M(39) M(40) M(41) M(42) M(43) M(44) M(45) M(46) M(47) \
                  M(48) M(49) M(50) M(51) M(52) M(53) M(54) M(55) M(56) M(57) M(58) M(59) M(60) M(61) M(62) M(63)
#define RL2_16(M) M(0,1) M(2,3) M(4,5) M(6,7) M(8,9) M(10,11) M(12,13) M(14,15)
#define RL2_32(M) RL2_16(M) M(16,17) M(18,19) M(20,21) M(22,23) M(24,25) M(26,27) M(28,29) M(30,31)
#define RL2_64(M) RL2_32(M) M(32,33) M(34,35) M(36,37) M(38,39) M(40,41) M(42,43) M(44,45) M(46,47) \
                  M(48,49) M(50,51) M(52,53) M(54,55) M(56,57) M(58,59) M(60,61) M(62,63)

// ---------------- init: deg=1 (self loop), counts=0 ----------------
__global__ void k_init(float* __restrict__ deg, int* __restrict__ counts){
  int i = blockIdx.x*256 + threadIdx.x;
  if (i < NN) deg[i] = 1.0f;
  if (i < NG) counts[i] = 0;
}

// ---------------- degree (edges) + per-graph node counts ----------------
__global__ void k_degcnt(const int* __restrict__ ei, const int* __restrict__ batch,
                         float* __restrict__ deg, int* __restrict__ counts){
  int i = blockIdx.x*256 + threadIdx.x;
  if (i < NE) atomicAdd(&deg[ei[NE + i]], 1.0f);
  if (i < NN) atomicAdd(&counts[batch[i]], 1);
}

// ---------------- exclusive scan of counts -> starts (1 block, 512 thr) ----------------
__global__ void k_scan(const int* __restrict__ counts, int* __restrict__ starts){
  __shared__ int sc[NG];
  int t = threadIdx.x;
  sc[t] = counts[t]; __syncthreads();
  for (int off = 1; off < NG; off <<= 1){
    int v = (t >= off) ? sc[t-off] : 0;
    __syncthreads();
    sc[t] += v;
    __syncthreads();
  }
  starts[t] = sc[t] - counts[t];
}

__global__ void k_dinv(const float* __restrict__ deg, float* __restrict__ dinv){
  int i = blockIdx.x*256 + threadIdx.x;
  if (i < NN) dinv[i] = 1.0f / sqrtf(fmaxf(deg[i], 1.0f));
}

// ---------------- xa = x @ w1  (no bias yet) ----------------
__global__ void k_lin1(const float* __restrict__ x, const float* __restrict__ w1,
                       float* __restrict__ xa){
  __shared__ float w[FIN*HG];
  int tid = threadIdx.x;
  for (int i = tid; i < FIN*HG; i += 256) w[i] = w1[i];
  __syncthreads();
  int id = blockIdx.x*256 + tid;
  if (id >= NN*HG) return;
  int node = id >> 4, f = id & 15;
  const float* xr = x + (size_t)node*FIN;
  float acc = 0.0f;
#pragma unroll
  for (int k = 0; k < FIN; k++) acc = fmaf(xr[k], w[k*HG + f], acc);
  xa[id] = acc;
}

// ---------------- agg = v * dinv^2 (self-loop term) ----------------
__global__ void k_selfinit(const float* __restrict__ v, const float* __restrict__ dinv,
                           float* __restrict__ agg){
  int id = blockIdx.x*256 + threadIdx.x;
  if (id >= NN*HG) return;
  float di = dinv[id >> 4];
  agg[id] = v[id] * di * di;
}

// ---------------- agg[dst] += v[src]*dinv[src]*dinv[dst] over edges ----------------
__global__ void k_scatter(const int* __restrict__ ei, const float* __restrict__ v,
                          const float* __restrict__ dinv, float* __restrict__ agg){
  int id = blockIdx.x*256 + threadIdx.x;
  if (id >= NE*HG) return;
  int e = id >> 4, f = id & 15;
  int s = ei[e], d = ei[NE + e];
  float nv = dinv[s] * dinv[d];
  atomicAdd(&agg[d*HG + f], v[s*HG + f] * nv);
}

// ---------------- hb = relu(agg + b1) @ w2 ----------------
__global__ void k_relu_lin(const float* __restrict__ agg, const float* __restrict__ b1,
                           const float* __restrict__ w2, float* __restrict__ hb){
  __shared__ float w[HG*HG];
  __shared__ float bb[HG];
  int tid = threadIdx.x;
  if (tid < HG*HG) w[tid] = w2[tid];
  if (tid < HG) bb[tid] = b1[tid];
  __syncthreads();
  int id = blockIdx.x*256 + tid;
  if (id >= NN*HG) return;
  int node = id >> 4, f = id & 15;
  const float* ar = agg + (size_t)node*HG;
  float acc = 0.0f;
#pragma unroll
  for (int k = 0; k < HG; k++){
    float h = fmaxf(ar[k] + bb[k], 0.0f);
    acc = fmaf(h, w[k*HG + f], acc);
  }
  hb[id] = acc;
}

// ---------------- h2 = relu(agg + b2) ----------------
__global__ void k_relu(const float* __restrict__ agg, const float* __restrict__ b2,
                       float* __restrict__ h2){
  int id = blockIdx.x*256 + threadIdx.x;
  if (id >= NN*HG) return;
  h2[id] = fmaxf(agg[id] + b2[id & 15], 0.0f);
}

// ---------------- BiLSTM layer 0: one wave per (graph, dir), no LDS, no barriers ----------------
// Lane layout: j = lane&31, half = lane>>5. Gates: gA = half*32+j (i or f),
// gB = 64+half*32+j (g or o). half==1 lanes own c_j, h_j; h broadcast via readlane.
__global__ __launch_bounds__(64, 1) void k_lstm0(
    const float* __restrict__ h2, const int* __restrict__ starts, const int* __restrict__ counts,
    const float* __restrict__ wih, const float* __restrict__ whh,
    const float* __restrict__ bih, const float* __restrict__ bhh,
    float* __restrict__ out0)
{
  const int g = blockIdx.x >> 1, dir = blockIdx.x & 1;
  const int lane = threadIdx.x;
  const int j = lane & 31, half = lane >> 5;
  const int gA = half*32 + j, gB = 64 + half*32 + j;
  const float* wihd = wih + (size_t)dir*128*HG;
  const float* whhd = whh + (size_t)dir*128*HL;
  // named-scalar weights: force VGPR residency (arrays spilled in R1 -> 48GB L1/L2 stream)
#define DWA0(i) float wa##i = wihd[gA*HG + i];
#define DWB0(i) float wb##i = wihd[gB*HG + i];
#define DUA0(i) float ua##i = whhd[gA*HL + i];
#define DUB0(i) float ub##i = whhd[gB*HL + i];
  RL1_16(DWA0) RL1_16(DWB0) RL1_32(DUA0) RL1_32(DUB0)
  const float pbA = bih[dir*128 + gA] + bhh[dir*128 + gA];
  const float pbB = bih[dir*128 + gB] + bhh[dir*128 + gB];
  int cnt = counts[g]; if (cnt > TS) cnt = TS;
  const int s0 = starts[g];
  float* outg = out0 + (size_t)g*TS*64 + dir*32;

  // backward dir: with all-zero effective biases, zero input keeps state exactly 0,
  // so steps t >= cnt produce h == 0. Guard with a runtime bias check.
  unsigned long long zb = __ballot(pbA == 0.0f && pbB == 0.0f);
  bool allzero = (zb == ~0ull);

  int t0, dt, nst;
  if (dir == 0){ t0 = 0; dt = 1; nst = TS; }
  else if (allzero){
    for (int t = cnt; t < TS; ++t) if (half) outg[(size_t)t*64 + j] = 0.0f;
    t0 = cnt - 1; dt = -1; nst = cnt;
  } else { t0 = TS - 1; dt = -1; nst = TS; }

  const int lf = lane & 15;
  float xc = 0.0f, xn = 0.0f;
  if (nst > 0){
    if (t0 >= 0 && t0 < cnt) xc = h2[(size_t)(s0 + t0)*HG + lf];
    int tn = t0 + dt;
    if (tn >= 0 && tn < cnt) xn = h2[(size_t)(s0 + tn)*HG + lf];
  }
  float hprev = 0.0f, c = 0.0f;

  for (int tt = 0; tt < nst; ++tt){
    int t = t0 + tt*dt;
    int tp = t + 2*dt;                 // prefetch 2 ahead (hide global latency)
    float xf = 0.0f;
    if (tp >= 0 && tp < cnt) xf = h2[(size_t)(s0 + tp)*HG + lf];
    float a0 = pbA, a1 = 0.0f, b0 = pbB, b1 = 0.0f;
    if (t < cnt){
#define FMX0(i,k) { float s_0 = rl(xc,i); float s_1 = rl(xc,k); \
      a0 = fmaf(s_0, wa##i, a0); b0 = fmaf(s_0, wb##i, b0); \
      a1 = fmaf(s_1, wa##k, a1); b1 = fmaf(s_1, wb##k, b1); }
      RL2_16(FMX0)
    }
#define FMH0(i,k) { float s_0 = rl(hprev,32+i); float s_1 = rl(hprev,32+k); \
    a0 = fmaf(s_0, ua##i, a0); b0 = fmaf(s_0, ub##i, b0); \
    a1 = fmaf(s_1, ua##k, a1); b1 = fmaf(s_1, ub##k, b1); }
    RL2_32(FMH0)
    float aA = a0 + a1, aB = b0 + b1;
    float sA = sigf(aA);                       // half0: sig(i); half1: sig(f)
    float u  = half ? aB : (aB + aB);
    float sB = rcpf(1.0f + __expf(-u));
    float vB = half ? sB : (sB + sB - 1.0f);   // half0: tanh(g); half1: sig(o)
    float p  = sA * vB;                        // half0: sig(i)*tanh(g)
    float pj = __shfl(p, j);                   // lane 32+j pulls p_j from lane j
    c = fmaf(sA, c, pj);                       // meaningful on half1
    float h = vB * tanhfast(c);                // half1: sig(o)*tanh(c)
    if (half) outg[(size_t)t*64 + j] = h;
    hprev = h;
    xc = xn; xn = xf;
  }
}

// ---------------- BiLSTM layer 1 + mean pooling, no LDS, no barriers ----------------
__global__ __launch_bounds__(64, 1) void k_lstm1(
    const float* __restrict__ gl0, const float* __restrict__ wih, const float* __restrict__ whh,
    const float* __restrict__ bih, const float* __restrict__ bhh,
    float* __restrict__ pooled)
{
  const int g = blockIdx.x >> 1, dir = blockIdx.x & 1;
  const int lane = threadIdx.x;
  const int j = lane & 31, half = lane >> 5;
  const int gA = half*32 + j, gB = 64 + half*32 + j;
  const float* wihd = wih + (size_t)dir*128*64;
  const float* whhd = whh + (size_t)dir*128*HL;
#define DWA1(i) float wa##i = wihd[gA*64 + i];
#define DWB1(i) float wb##i = wihd[gB*64 + i];
#define DUA1(i) float ua##i = whhd[gA*HL + i];
#define DUB1(i) float ub##i = whhd[gB*HL + i];
  RL1_64(DWA1) RL1_64(DWB1) RL1_32(DUA1) RL1_32(DUB1)
  const float pbA = bih[dir*128 + gA] + bhh[dir*128 + gA];
  const float pbB = bih[dir*128 + gB] + bhh[dir*128 + gB];
  const float* gin = gl0 + (size_t)g*TS*64;

  const int t0 = dir ? (TS - 1) : 0, dt = dir ? -1 : 1;
  float xc = gin[(size_t)t0*64 + lane];
  float xn = gin[(size_t)(t0 + dt)*64 + lane];
  float hprev = 0.0f, c = 0.0f, hsum = 0.0f;

  for (int tt = 0; tt < TS; ++tt){
    int t = t0 + tt*dt;
    int tp = t + 2*dt;
    float xf = 0.0f;
    if ((unsigned)tp < TS) xf = gin[(size_t)tp*64 + lane];
    float a0 = pbA, a1 = 0.0f, b0 = pbB, b1 = 0.0f;
#define FMX1(i,k) { float s_0 = rl(xc,i); float s_1 = rl(xc,k); \
    a0 = fmaf(s_0, wa##i, a0); b0 = fmaf(s_0, wb##i, b0); \
    a1 = fmaf(s_1, wa##k, a1); b1 = fmaf(s_1, wb##k, b1); }
    RL2_64(FMX1)
#define FMH1(i,k) { float s_0 = rl(hprev,32+i); float s_1 = rl(hprev,32+k); \
    a0 = fmaf(s_0, ua##i, a0); b0 = fmaf(s_0, ub##i, b0); \
    a1 = fmaf(s_1, ua##k, a1); b1 = fmaf(s_1, ub##k, b1); }
    RL2_32(FMH1)
    float aA = a0 + a1, aB = b0 + b1;
    float sA = sigf(aA);
    float u  = half ? aB : (aB + aB);
    float sB = rcpf(1.0f + __expf(-u));
    float vB = half ? sB : (sB + sB - 1.0f);
    float p  = sA * vB;
    float pj = __shfl(p, j);
    c = fmaf(sA, c, pj);
    float h = vB * tanhfast(c);
    hprev = h;
    hsum += h;
    xc = xn; xn = xf;
  }
  if (half) pooled[(size_t)g*64 + dir*32 + j] = hsum * (1.0f/(float)TS);
}

// ---------------- FC: out = pooled @ fc_w + fc_b ----------------
__global__ void k_fc(const float* __restrict__ pooled, const float* __restrict__ fcw,
                     const float* __restrict__ fcb, float* __restrict__ out){
  __shared__ float p[64];
  int g = blockIdx.x, cix = threadIdx.x;
  if (cix < 64) p[cix] = pooled[(size_t)g*64 + cix];
  __syncthreads();
  float acc = fcb[cix];
#pragma unroll
  for (int k = 0; k < 64; k++) acc = fmaf(p[k], fcw[k*NC + cix], acc);
  out[(size_t)g*NC + cix] = acc;
}

extern "C" void kernel_launch(void* const* d_in, const int* in_sizes, int n_in,
                              void* d_out, int out_size, void* d_ws, size_t ws_size,
                              hipStream_t stream) {
  const float* x        = (const float*)d_in[0];
  const int*   ei       = (const int*)  d_in[1];
  const int*   batch    = (const int*)  d_in[2];
  const float* gcn_w1   = (const float*)d_in[3];
  const float* gcn_b1   = (const float*)d_in[4];
  const float* gcn_w2   = (const float*)d_in[5];
  const float* gcn_b2   = (const float*)d_in[6];
  const float* l0_wih   = (const float*)d_in[7];
  const float* l0_whh   = (const float*)d_in[8];
  const float* l0_bih   = (const float*)d_in[9];
  const float* l0_bhh   = (const float*)d_in[10];
  const float* l1_wih   = (const float*)d_in[11];
  const float* l1_whh   = (const float*)d_in[12];
  const float* l1_bih   = (const float*)d_in[13];
  const float* l1_bhh   = (const float*)d_in[14];
  const float* fc_w     = (const float*)d_in[15];
  const float* fc_b     = (const float*)d_in[16];
  float* out = (float*)d_out;

  // workspace layout (floats)
  float* ws   = (float*)d_ws;
  float* B0   = ws;                    // N*16 : xa -> agg2
  float* B1   = B0 + (size_t)NN*HG;    // N*16 : agg1 -> h2
  float* B2   = B1 + (size_t)NN*HG;    // N*16 : hb
  float* deg  = B2 + (size_t)NN*HG;    // N
  float* dinv = deg + NN;              // N
  int*   counts = (int*)(dinv + NN);   // 512
  int*   starts = counts + NG;         // 512
  float* pooled = (float*)(starts + NG);      // 512*64
  float* out0   = pooled + (size_t)NG*64;     // 512*1024*64
  size_t needed = ((size_t)(out0 - ws) + (size_t)NG*TS*64) * sizeof(float);
  if (ws_size < needed) return;  // fail loudly (poisoned d_out) rather than corrupt

  k_init   <<<(NN+255)/256, 256, 0, stream>>>(deg, counts);
  k_degcnt <<<(NE+255)/256, 256, 0, stream>>>(ei, batch, deg, counts);
  k_scan   <<<1, NG, 0, stream>>>(counts, starts);
  k_dinv   <<<(NN+255)/256, 256, 0, stream>>>(deg, dinv);
  k_lin1   <<<(NN*HG)/256, 256, 0, stream>>>(x, gcn_w1, B0);
  k_selfinit<<<(NN*HG)/256, 256, 0, stream>>>(B0, dinv, B1);
  k_scatter<<<(NE*HG)/256, 256, 0, stream>>>(ei, B0, dinv, B1);
  k_relu_lin<<<(NN*HG)/256, 256, 0, stream>>>(B1, gcn_b1, gcn_w2, B2);
  k_selfinit<<<(NN*HG)/256, 256, 0, stream>>>(B2, dinv, B0);
  k_scatter<<<(NE*HG)/256, 256, 0, stream>>>(ei, B2, dinv, B0);
  k_relu   <<<(NN*HG)/256, 256, 0, stream>>>(B0, gcn_b2, B1);
  k_lstm0  <<<NG*2, 64, 0, stream>>>(B1, starts, counts, l0_wih, l0_whh, l0_bih, l0_bhh, out0);
  k_lstm1  <<<NG*2, 64, 0, stream>>>(out0, l1_wih, l1_whh, l1_bih, l1_bhh, pooled);
  k_fc     <<<NG, NC, 0, stream>>>(pooled, fc_w, fc_b, out);
}